// Round 3
// baseline (224.150 us; speedup 1.0000x reference)
//
#include <hip/hip_runtime.h>

// Problem constants: N=262144, D=32, Q=4, K=256
#define DIMS 32
#define NQ   4
#define KC   256
#define BETA 0.25f
#define FLTMAX 3.402823466e38f
#define NG   4   // point-groups of 16 per wave (64 points/wave)

typedef __attribute__((ext_vector_type(8))) short  short8;   // 8 bf16 (4 VGPRs)
typedef __attribute__((ext_vector_type(4))) float  floatx4;  // MFMA acc

// ROUND-11 (vs r10 FAILED absmax 6.39; r9 harness-validated 147us dispatch):
// r10 bundled three changes; the two numerics-adjacent ones (permlane32 asm
// butterfly, +hrn drop -> mixed-sign packed scores) are REVERTED to r9's
// harness-validated forms. KEPT: the pure-structural NG=4 (64 points/wave):
// halves barriers/DMA-waits/hn-broadcasts/tile-ds_reads per point, doubles
// independent MFMA->min chains (ILP at fixed residency). Grid 2048 -> 1024.
// Numerics are bit-identical to r9 (positive packed scores, shfl_xor
// butterflies, same eps + exact rescan).
__device__ __forceinline__ void gl2lds16(const void* g, void* lp) {
    __builtin_amdgcn_global_load_lds(
        (__attribute__((address_space(1))) void*)(g),
        (__attribute__((address_space(3))) void*)(lp), 16, 0, 0);
}

__global__ void rvq_prep(const float* __restrict__ cb,      // [NQ, KC, DIMS]
                         short* __restrict__ ws_hi,         // [NQ*1024*8]
                         short* __restrict__ ws_lo,         // [NQ*1024*8]
                         float* __restrict__ ws_hn,         // [NQ*KC]
                         float* __restrict__ out_loss)
{
    const int q = blockIdx.x;
    const int t = threadIdx.x;
    if (q == 0 && t == 0) *out_loss = 0.f;
    const float* cbq = cb + (size_t)q * KC * DIMS;

    // exact fp32 half-norms, thread t <-> code t
    {
        const float4* c4 = (const float4*)(cbq + (size_t)t * DIMS);
        float s0 = 0.f, s1 = 0.f, s2 = 0.f, s3 = 0.f;
        #pragma unroll
        for (int j = 0; j < 8; ++j) {
            float4 f = c4[j];
            s0 = fmaf(f.x, f.x, s0); s1 = fmaf(f.y, f.y, s1);
            s2 = fmaf(f.z, f.z, s2); s3 = fmaf(f.w, f.w, s3);
        }
        ws_hn[(q << 8) + t] = 0.5f * ((s0 + s1) + (s2 + s3));
    }

    // negated trunc-split codebook; entry e = tt*64 + qo*16 + cl, 16 B each
    #pragma unroll
    for (int it = 0; it < 4; ++it) {
        int e = it * 256 + t;
        const float4* src = (const float4*)(cbq + (size_t)((e >> 6) * 16 + (e & 15)) * DIMS
                                            + ((e >> 4) & 3) * 8);
        float4 f0 = src[0], f1 = src[1];
        unsigned u[8];
        u[0]=__float_as_uint(f0.x)^0x80000000u; u[1]=__float_as_uint(f0.y)^0x80000000u;
        u[2]=__float_as_uint(f0.z)^0x80000000u; u[3]=__float_as_uint(f0.w)^0x80000000u;
        u[4]=__float_as_uint(f1.x)^0x80000000u; u[5]=__float_as_uint(f1.y)^0x80000000u;
        u[6]=__float_as_uint(f1.z)^0x80000000u; u[7]=__float_as_uint(f1.w)^0x80000000u;
        int4 hp, lp;
        int* hpi = (int*)&hp; int* lpi = (int*)&lp;
        #pragma unroll
        for (int p = 0; p < 4; ++p) {
            unsigned a = u[2*p], b = u[2*p+1];
            hpi[p] = (int)((b & 0xFFFF0000u) | (a >> 16));
            float ea = __uint_as_float(a) - __uint_as_float(a & 0xFFFF0000u);
            float eb = __uint_as_float(b) - __uint_as_float(b & 0xFFFF0000u);
            unsigned ua = __float_as_uint(ea), ub = __float_as_uint(eb);
            lpi[p] = (int)((ub & 0xFFFF0000u) | (ua >> 16));
        }
        *(int4*)(&ws_hi[(size_t)((q << 10) + e) << 3]) = hp;
        *(int4*)(&ws_lo[(size_t)((q << 10) + e) << 3]) = lp;
    }
}

__launch_bounds__(256, 2)
__global__ void rvq_kernel(const float* __restrict__ x,
                           const float* __restrict__ cb,      // [NQ, KC, DIMS] fp32 (gather/rescan)
                           const short* __restrict__ ws_hi,   // preconverted hi
                           const short* __restrict__ ws_lo,   // preconverted lo
                           const float* __restrict__ ws_hn,   // half-norms
                           float* __restrict__ out_xq,        // [N, DIMS]
                           float* __restrict__ out_loss,      // [1] pre-zeroed by prep
                           float* __restrict__ out_idx)       // [N, NQ] as float
{
    // entry e = tt*64 + qo*16 + cl  <->  code tt*16+cl, dim-octet qo; 16 B each.
    __shared__ __align__(16) short s_hi[1024 * 8];   // 16 KB
    __shared__ __align__(16) short s_lo[1024 * 8];   // 16 KB
    __shared__ float s_hn[NQ * KC];                  // 4 KB: 0.5*||c||^2, all stages
    __shared__ float s_ws[4];

    const int t  = threadIdx.x;
    const int l  = t & 63;
    const int w  = t >> 6;
    const int qo = l >> 4;       // dim-octet (0..3)
    const int cl = l & 15;       // point-in-group / code-in-tile

    const int base = blockIdx.x * (64 * NG) + w * (16 * NG);   // wave covers 64 points

    // ---- issue stage-0 codebook DMA immediately (hides L2 latency) ----
    #pragma unroll
    for (int it = 0; it < 4; ++it) {
        const int eb = (it * 4 + w) * 64;            // wave-uniform entry base
        gl2lds16(ws_hi + ((size_t)(eb + l) << 3), &s_hi[eb << 3]);
        gl2lds16(ws_lo + ((size_t)(eb + l) << 3), &s_lo[eb << 3]);
    }
    // ---- all-stage half-norms into LDS once ----
    #pragma unroll
    for (int i = 0; i < 4; ++i) s_hn[(i << 8) + t] = ws_hn[(i << 8) + t];

    // ---- residuals: [group][8 dims], 32 VGPRs ----
    float r[NG][8];
    #pragma unroll
    for (int g = 0; g < NG; ++g) {
        const float4* xp = (const float4*)(x + (size_t)(base + g*16 + cl) * DIMS + qo * 8);
        float4 a = xp[0], c = xp[1];
        r[g][0]=a.x; r[g][1]=a.y; r[g][2]=a.z; r[g][3]=a.w;
        r[g][4]=c.x; r[g][5]=c.y; r[g][6]=c.z; r[g][7]=c.w;
    }

    float la = 0.f;   // sum over own dims of ||r_new||^2, all stages

    for (int q = 0; q < NQ; ++q) {
        const float* cbq = cb + (size_t)q * KC * DIMS;
        const float* hnq = &s_hn[q << 8];

        // ---- B-fragments: trunc-split bf16 of residual (unnegated) ----
        // (no LDS dependency -> runs while stage-q DMA is in flight)
        short8 rh[NG], rl[NG];
        #pragma unroll
        for (int g = 0; g < NG; ++g) {
            int4 hp, lp;
            int* hpi = (int*)&hp; int* lpi = (int*)&lp;
            #pragma unroll
            for (int p = 0; p < 4; ++p) {
                unsigned a = __float_as_uint(r[g][2*p]);
                unsigned b = __float_as_uint(r[g][2*p+1]);
                hpi[p] = (int)((b & 0xFFFF0000u) | (a >> 16));
                float ea = r[g][2*p]   - __uint_as_float(a & 0xFFFF0000u);
                float eb = r[g][2*p+1] - __uint_as_float(b & 0xFFFF0000u);
                unsigned ua = __float_as_uint(ea), ub = __float_as_uint(eb);
                lpi[p] = (int)((ub & 0xFFFF0000u) | (ua >> 16));
            }
            rh[g] = *(short8*)&hp;
            rl[g] = *(short8*)&lp;
        }

        // ---- ||r||^2 per point (every lane ends with its point's value) ----
        float rn[NG], hrn[NG];
        #pragma unroll
        for (int g = 0; g < NG; ++g) {
            float p0 = 0.f;
            #pragma unroll
            for (int j = 0; j < 8; ++j) p0 = fmaf(r[g][j], r[g][j], p0);
            p0 += __shfl_xor(p0, 16);
            p0 += __shfl_xor(p0, 32);
            rn[g] = p0;
            hrn[g] = 0.5f * p0;
        }

        asm volatile("s_waitcnt vmcnt(0)" ::: "memory");
        __syncthreads();   // staged s_hi/s_lo (and, q=0, s_hn) ready for all waves

        // ---- MFMA tile loop ----
        float m1[NG][4], m2[NG][4];
        #pragma unroll
        for (int g = 0; g < NG; ++g)
            #pragma unroll
            for (int i = 0; i < 4; ++i) { m1[g][i] = FLTMAX; m2[g][i] = FLTMAX; }

        #pragma unroll 4
        for (int tt = 0; tt < 16; ++tt) {
            const short8 ch  = *(const short8*)(&s_hi[((tt << 6) + l) << 3]);
            const short8 cl8 = *(const short8*)(&s_lo[((tt << 6) + l) << 3]);
            const float4 hn4 = *(const float4*)(&hnq[(tt << 4) + (qo << 2)]);  // broadcast
            #pragma unroll
            for (int g = 0; g < NG; ++g) {
                floatx4 acc = {hn4.x + hrn[g], hn4.y + hrn[g],
                               hn4.z + hrn[g], hn4.w + hrn[g]};
                acc = __builtin_amdgcn_mfma_f32_16x16x32_bf16(ch,  rh[g], acc, 0, 0, 0);
                acc = __builtin_amdgcn_mfma_f32_16x16x32_bf16(ch,  rl[g], acc, 0, 0, 0);
                acc = __builtin_amdgcn_mfma_f32_16x16x32_bf16(cl8, rh[g], acc, 0, 0, 0);
                #pragma unroll
                for (int i = 0; i < 4; ++i) {
                    float pm = __uint_as_float((__float_as_uint(acc[i]) & 0xFFFFFF00u)
                                               | (unsigned)((tt << 2) | i));
                    float mx = fmaxf(pm, m1[g][i]);
                    m1[g][i] = fminf(pm, m1[g][i]);
                    m2[g][i] = fminf(m2[g][i], mx);
                }
            }
        }

        __syncthreads();   // all waves done reading s_hi/s_lo for stage q

        // ---- issue stage-(q+1) codebook DMA; overlaps everything below ----
        if (q < NQ - 1) {
            const short* srch = ws_hi + ((size_t)(q + 1) << 13);
            const short* srcl = ws_lo + ((size_t)(q + 1) << 13);
            #pragma unroll
            for (int it = 0; it < 4; ++it) {
                const int eb = (it * 4 + w) * 64;
                gl2lds16(srch + ((size_t)(eb + l) << 3), &s_hi[eb << 3]);
                gl2lds16(srcl + ((size_t)(eb + l) << 3), &s_lo[eb << 3]);
            }
        }

        int bip[NG]; bool flg[NG];
        #pragma unroll
        for (int g = 0; g < NG; ++g) {
            // resolve packed (tt<<2)|i -> full code tt*16 + qo*4 + i (order-preserving)
            #pragma unroll
            for (int i = 0; i < 4; ++i) {
                unsigned u = __float_as_uint(m1[g][i]);
                unsigned low = u & 0xFFu;
                unsigned full = ((low & 0xFCu) << 2) | ((unsigned)qo << 2) | (low & 3u);
                m1[g][i] = __uint_as_float((u & 0xFFFFFF00u) | full);
            }
            // merge 4 regs -> (M1, M2)
            float p1 = fminf(m1[g][0], m1[g][1]);
            float ph = fmaxf(m1[g][0], m1[g][1]);
            float p2 = fminf(fminf(m2[g][0], m2[g][1]), ph);
            float s1 = fminf(m1[g][2], m1[g][3]);
            float sh = fmaxf(m1[g][2], m1[g][3]);
            float s2 = fminf(fminf(m2[g][2], m2[g][3]), sh);
            float hh = fmaxf(p1, s1);
            float M1 = fminf(p1, s1);
            float M2 = fminf(fminf(p2, s2), hh);
            // merge across the 4 owner lanes (xor 16, 32) — lands where it's consumed
            #pragma unroll
            for (int off = 16; off <= 32; off <<= 1) {
                float o1 = __shfl_xor(M1, off);
                float o2 = __shfl_xor(M2, off);
                float h2 = fmaxf(M1, o1);
                M1 = fminf(M1, o1);
                M2 = fminf(fminf(M2, o2), h2);
            }
            bip[g] = (int)(__float_as_uint(M1) & 0xFFu);
            float a1 = __uint_as_float(__float_as_uint(M1) & 0xFFFFFF00u);
            float a2 = __uint_as_float(__float_as_uint(M2) & 0xFFFFFF00u);
            // trunc-split bf16x3 error + packing quantization, 4x margin (half-units)
            float eps = fmaf(sqrtf(rn[g]), 1.5e-3f, fmaf(fabsf(a1), 3e-5f, 1e-6f));
            flg[g] = (a2 - a1) < eps;
        }

        // ---- rare: exact fp32 wave-cooperative rescan of ambiguous points ----
        #pragma unroll
        for (int g = 0; g < NG; ++g) {
            unsigned long long bm = __ballot((l < 16) && flg[g]);
            while (bm) {
                int p = __ffsll(bm) - 1;
                bm &= bm - 1;
                float rp[32];
                #pragma unroll
                for (int qq = 0; qq < 4; ++qq)
                    #pragma unroll
                    for (int j = 0; j < 8; ++j)
                        rp[qq*8 + j] = __shfl(r[g][j], qq*16 + p);
                float bests = FLTMAX; int bestk = 0;
                #pragma unroll
                for (int c = 0; c < 4; ++c) {
                    int k = (c << 6) + l;
                    const float4* ck = (const float4*)(cbq + (size_t)k * DIMS);
                    float a0=0.f,a1=0.f,a2=0.f,a3=0.f;
                    #pragma unroll
                    for (int j = 0; j < 8; ++j) {
                        float4 f = ck[j];
                        a0 = fmaf(rp[4*j+0], f.x, a0);
                        a1 = fmaf(rp[4*j+1], f.y, a1);
                        a2 = fmaf(rp[4*j+2], f.z, a2);
                        a3 = fmaf(rp[4*j+3], f.w, a3);
                    }
                    float sc = fmaf(-2.f, (a0+a1)+(a2+a3), 2.f * hnq[k]);
                    bool lt = sc < bests;
                    bests = lt ? sc : bests;  bestk = lt ? k : bestk;
                }
                #pragma unroll
                for (int off = 1; off < 64; off <<= 1) {
                    float so = __shfl_xor(bests, off);
                    int   ko = __shfl_xor(bestk, off);
                    bool take = (so < bests) || (so == bests && ko < bestk);
                    bests = take ? so : bests;
                    bestk = take ? ko : bestk;
                }
                if (cl == p) bip[g] = bestk;
            }
        }

        // ---- gather chosen codes (exact fp32), update residual, loss, indices ----
        #pragma unroll
        for (int g = 0; g < NG; ++g) {
            const float4* cq = (const float4*)(cbq + (size_t)bip[g] * DIMS + qo * 8);
            float4 c0 = cq[0], c1 = cq[1];
            r[g][0]-=c0.x; r[g][1]-=c0.y; r[g][2]-=c0.z; r[g][3]-=c0.w;
            r[g][4]-=c1.x; r[g][5]-=c1.y; r[g][6]-=c1.z; r[g][7]-=c1.w;
            #pragma unroll
            for (int j = 0; j < 8; ++j) la = fmaf(r[g][j], r[g][j], la);
            if (l < 16)
                out_idx[(size_t)(base + g*16 + l) * NQ + q] = (float)bip[g];
        }
    }

    // ---- epilogue: x_q = x - r_final ----
    #pragma unroll
    for (int g = 0; g < NG; ++g) {
        size_t o = (size_t)(base + g*16 + cl) * DIMS + qo * 8;
        const float4* xp = (const float4*)(x + o);
        float4 a = xp[0], c = xp[1];
        float4* op = (float4*)(out_xq + o);
        op[0] = make_float4(a.x - r[g][0], a.y - r[g][1], a.z - r[g][2], a.w - r[g][3]);
        op[1] = make_float4(c.x - r[g][4], c.y - r[g][5], c.z - r[g][6], c.w - r[g][7]);
    }

    // ---- loss: wave -> block -> one atomicAdd ----
    float v = la;
    #pragma unroll
    for (int off = 1; off < 64; off <<= 1)
        v += __shfl_xor(v, off);
    if (l == 0) s_ws[w] = v;
    __syncthreads();
    if (t == 0) {
        const float scale = (1.0f + BETA) / ((float)NQ * 262144.0f * (float)DIMS);
        atomicAdd(out_loss, (s_ws[0] + s_ws[1] + s_ws[2] + s_ws[3]) * scale);
    }
}

extern "C" void kernel_launch(void* const* d_in, const int* in_sizes, int n_in,
                              void* d_out, int out_size, void* d_ws, size_t ws_size,
                              hipStream_t stream) {
    const float* x  = (const float*)d_in[0];   // [N, 32]
    const float* cb = (const float*)d_in[1];   // [4, 256, 32]
    float* out = (float*)d_out;

    const int N = in_sizes[0] / DIMS;          // 262144
    float* out_xq   = out;
    float* out_loss = out + (size_t)N * DIMS;
    float* out_idx  = out + (size_t)N * DIMS + 1;

    // workspace layout: hi [4*1024*16B] | lo [4*1024*16B] | hn [4*256*4B] = 132 KB
    short* ws_hi = (short*)d_ws;
    short* ws_lo = (short*)((char*)d_ws + 65536);
    float* ws_hn = (float*)((char*)d_ws + 131072);

    rvq_prep<<<dim3(NQ), dim3(KC), 0, stream>>>(cb, ws_hi, ws_lo, ws_hn, out_loss);
    rvq_kernel<<<dim3(N / (64 * NG)), dim3(256), 0, stream>>>(x, cb, ws_hi, ws_lo, ws_hn,
                                                              out_xq, out_loss, out_idx);
}

// Round 4
// 204.710 us; speedup vs baseline: 1.0950x; 1.0950x over previous
//
#include <hip/hip_runtime.h>

// Problem constants: N=262144, D=32, Q=4, K=256
#define DIMS 32
#define NQ   4
#define KC   256
#define BETA 0.25f
#define FLTMAX 3.402823466e38f

typedef __attribute__((ext_vector_type(8))) short  short8;   // 8 bf16 (4 VGPRs)
typedef __attribute__((ext_vector_type(4))) float  floatx4;  // MFMA acc

// ROUND-12 (vs r11 FAILED-perf: NG=4 spilled under the empirical 128-VGPR cap
// of __launch_bounds__(256,2) -> FETCH 17.6->48.4MB, WRITE 37.3->75.2MB, 160us;
// vs r9 harness-validated 147us):
//  * REVERT to NG=2 (r9's validated register budget, 124 VGPR, no spill).
//  * DROP codebook LDS staging entirely. The preconverted hi/lo workspace is
//    32KB/stage and identical across all 2048 blocks -> perfectly L2-resident.
//    Tile loop now reads ch/cl8 via coalesced global_load_dwordx4 (1KB/wave
//    per load, same addrs across blocks). This removes ALL per-stage barriers
//    and vmcnt(0) drains (waves fully independent until loss reduction) and
//    shrinks LDS to 4KB (hn only, 1 barrier at entry) -> residency VGPR-bound
//    at 128 (up to 16 waves/CU vs ~6).
//  * #pragma unroll 4 on the tile loop -> 8 loads in flight per quad to hide
//    ~200cyc L2 latency under MFMA+min work.
// Numerics bit-identical to r9 (trunc-split triple MFMA, +hrn positive packed
// scores, shfl_xor butterflies, same eps + exact rescan).

__global__ void rvq_prep(const float* __restrict__ cb,      // [NQ, KC, DIMS]
                         short* __restrict__ ws_hi,         // [NQ*1024*8]
                         short* __restrict__ ws_lo,         // [NQ*1024*8]
                         float* __restrict__ ws_hn,         // [NQ*KC]
                         float* __restrict__ out_loss)
{
    const int q = blockIdx.x;
    const int t = threadIdx.x;
    if (q == 0 && t == 0) *out_loss = 0.f;
    const float* cbq = cb + (size_t)q * KC * DIMS;

    // exact fp32 half-norms, thread t <-> code t
    {
        const float4* c4 = (const float4*)(cbq + (size_t)t * DIMS);
        float s0 = 0.f, s1 = 0.f, s2 = 0.f, s3 = 0.f;
        #pragma unroll
        for (int j = 0; j < 8; ++j) {
            float4 f = c4[j];
            s0 = fmaf(f.x, f.x, s0); s1 = fmaf(f.y, f.y, s1);
            s2 = fmaf(f.z, f.z, s2); s3 = fmaf(f.w, f.w, s3);
        }
        ws_hn[(q << 8) + t] = 0.5f * ((s0 + s1) + (s2 + s3));
    }

    // negated trunc-split codebook; entry e = tt*64 + qo*16 + cl, 16 B each
    #pragma unroll
    for (int it = 0; it < 4; ++it) {
        int e = it * 256 + t;
        const float4* src = (const float4*)(cbq + (size_t)((e >> 6) * 16 + (e & 15)) * DIMS
                                            + ((e >> 4) & 3) * 8);
        float4 f0 = src[0], f1 = src[1];
        unsigned u[8];
        u[0]=__float_as_uint(f0.x)^0x80000000u; u[1]=__float_as_uint(f0.y)^0x80000000u;
        u[2]=__float_as_uint(f0.z)^0x80000000u; u[3]=__float_as_uint(f0.w)^0x80000000u;
        u[4]=__float_as_uint(f1.x)^0x80000000u; u[5]=__float_as_uint(f1.y)^0x80000000u;
        u[6]=__float_as_uint(f1.z)^0x80000000u; u[7]=__float_as_uint(f1.w)^0x80000000u;
        int4 hp, lp;
        int* hpi = (int*)&hp; int* lpi = (int*)&lp;
        #pragma unroll
        for (int p = 0; p < 4; ++p) {
            unsigned a = u[2*p], b = u[2*p+1];
            hpi[p] = (int)((b & 0xFFFF0000u) | (a >> 16));
            float ea = __uint_as_float(a) - __uint_as_float(a & 0xFFFF0000u);
            float eb = __uint_as_float(b) - __uint_as_float(b & 0xFFFF0000u);
            unsigned ua = __float_as_uint(ea), ub = __float_as_uint(eb);
            lpi[p] = (int)((ub & 0xFFFF0000u) | (ua >> 16));
        }
        *(int4*)(&ws_hi[(size_t)((q << 10) + e) << 3]) = hp;
        *(int4*)(&ws_lo[(size_t)((q << 10) + e) << 3]) = lp;
    }
}

__launch_bounds__(256, 2)
__global__ void rvq_kernel(const float* __restrict__ x,
                           const float* __restrict__ cb,      // [NQ, KC, DIMS] fp32 (gather/rescan)
                           const short* __restrict__ ws_hi,   // preconverted hi (L2-resident)
                           const short* __restrict__ ws_lo,   // preconverted lo (L2-resident)
                           const float* __restrict__ ws_hn,   // half-norms
                           float* __restrict__ out_xq,        // [N, DIMS]
                           float* __restrict__ out_loss,      // [1] pre-zeroed by prep
                           float* __restrict__ out_idx)       // [N, NQ] as float
{
    __shared__ float s_hn[NQ * KC];                  // 4 KB: 0.5*||c||^2, all stages
    __shared__ float s_ws[4];

    const int t  = threadIdx.x;
    const int l  = t & 63;
    const int w  = t >> 6;
    const int qo = l >> 4;       // dim-octet (0..3)
    const int cl = l & 15;       // point-in-group / code-in-tile

    const int base = blockIdx.x * 128 + w * 32;   // wave covers 32 points (2 groups of 16)

    // ---- all-stage half-norms into LDS once ----
    #pragma unroll
    for (int i = 0; i < 4; ++i) s_hn[(i << 8) + t] = ws_hn[(i << 8) + t];

    // ---- residuals: [group][8 dims], 16 VGPRs ----
    float r[2][8];
    #pragma unroll
    for (int g = 0; g < 2; ++g) {
        const float4* xp = (const float4*)(x + (size_t)(base + g*16 + cl) * DIMS + qo * 8);
        float4 a = xp[0], c = xp[1];
        r[g][0]=a.x; r[g][1]=a.y; r[g][2]=a.z; r[g][3]=a.w;
        r[g][4]=c.x; r[g][5]=c.y; r[g][6]=c.z; r[g][7]=c.w;
    }

    __syncthreads();   // s_hn ready (the ONLY barrier until the loss epilogue)

    float la = 0.f;   // sum over own dims of ||r_new||^2, all stages

    for (int q = 0; q < NQ; ++q) {
        const float* cbq = cb + (size_t)q * KC * DIMS;
        const float* hnq = &s_hn[q << 8];
        const short8* gh = (const short8*)(ws_hi + ((size_t)q << 13));  // 1024 entries
        const short8* gl8 = (const short8*)(ws_lo + ((size_t)q << 13));

        // ---- B-fragments: trunc-split bf16 of residual (unnegated) ----
        short8 rh[2], rl[2];
        #pragma unroll
        for (int g = 0; g < 2; ++g) {
            int4 hp, lp;
            int* hpi = (int*)&hp; int* lpi = (int*)&lp;
            #pragma unroll
            for (int p = 0; p < 4; ++p) {
                unsigned a = __float_as_uint(r[g][2*p]);
                unsigned b = __float_as_uint(r[g][2*p+1]);
                hpi[p] = (int)((b & 0xFFFF0000u) | (a >> 16));
                float ea = r[g][2*p]   - __uint_as_float(a & 0xFFFF0000u);
                float eb = r[g][2*p+1] - __uint_as_float(b & 0xFFFF0000u);
                unsigned ua = __float_as_uint(ea), ub = __float_as_uint(eb);
                lpi[p] = (int)((ub & 0xFFFF0000u) | (ua >> 16));
            }
            rh[g] = *(short8*)&hp;
            rl[g] = *(short8*)&lp;
        }

        // ---- ||r||^2 per point (every lane ends with its point's value) ----
        float rn[2], hrn[2];
        #pragma unroll
        for (int g = 0; g < 2; ++g) {
            float p0 = 0.f;
            #pragma unroll
            for (int j = 0; j < 8; ++j) p0 = fmaf(r[g][j], r[g][j], p0);
            p0 += __shfl_xor(p0, 16);
            p0 += __shfl_xor(p0, 32);
            rn[g] = p0;
            hrn[g] = 0.5f * p0;
        }

        // ---- MFMA tile loop (codebook streamed from L2, no LDS, no barriers) ----
        float m1[2][4], m2[2][4];
        #pragma unroll
        for (int g = 0; g < 2; ++g)
            #pragma unroll
            for (int i = 0; i < 4; ++i) { m1[g][i] = FLTMAX; m2[g][i] = FLTMAX; }

        #pragma unroll 4
        for (int tt = 0; tt < 16; ++tt) {
            const short8 ch  = gh[(tt << 6) + l];
            const short8 cl8 = gl8[(tt << 6) + l];
            const float4 hn4 = *(const float4*)(&hnq[(tt << 4) + (qo << 2)]);  // LDS broadcast
            #pragma unroll
            for (int g = 0; g < 2; ++g) {
                floatx4 acc = {hn4.x + hrn[g], hn4.y + hrn[g],
                               hn4.z + hrn[g], hn4.w + hrn[g]};
                acc = __builtin_amdgcn_mfma_f32_16x16x32_bf16(ch,  rh[g], acc, 0, 0, 0);
                acc = __builtin_amdgcn_mfma_f32_16x16x32_bf16(ch,  rl[g], acc, 0, 0, 0);
                acc = __builtin_amdgcn_mfma_f32_16x16x32_bf16(cl8, rh[g], acc, 0, 0, 0);
                #pragma unroll
                for (int i = 0; i < 4; ++i) {
                    float pm = __uint_as_float((__float_as_uint(acc[i]) & 0xFFFFFF00u)
                                               | (unsigned)((tt << 2) | i));
                    float mx = fmaxf(pm, m1[g][i]);
                    m1[g][i] = fminf(pm, m1[g][i]);
                    m2[g][i] = fminf(m2[g][i], mx);
                }
            }
        }

        int bip[2]; bool flg[2];
        #pragma unroll
        for (int g = 0; g < 2; ++g) {
            // resolve packed (tt<<2)|i -> full code tt*16 + qo*4 + i (order-preserving)
            #pragma unroll
            for (int i = 0; i < 4; ++i) {
                unsigned u = __float_as_uint(m1[g][i]);
                unsigned low = u & 0xFFu;
                unsigned full = ((low & 0xFCu) << 2) | ((unsigned)qo << 2) | (low & 3u);
                m1[g][i] = __uint_as_float((u & 0xFFFFFF00u) | full);
            }
            // merge 4 regs -> (M1, M2)
            float p1 = fminf(m1[g][0], m1[g][1]);
            float ph = fmaxf(m1[g][0], m1[g][1]);
            float p2 = fminf(fminf(m2[g][0], m2[g][1]), ph);
            float s1 = fminf(m1[g][2], m1[g][3]);
            float sh = fmaxf(m1[g][2], m1[g][3]);
            float s2 = fminf(fminf(m2[g][2], m2[g][3]), sh);
            float hh = fmaxf(p1, s1);
            float M1 = fminf(p1, s1);
            float M2 = fminf(fminf(p2, s2), hh);
            // merge across the 4 owner lanes (xor 16, 32) — lands where it's consumed
            #pragma unroll
            for (int off = 16; off <= 32; off <<= 1) {
                float o1 = __shfl_xor(M1, off);
                float o2 = __shfl_xor(M2, off);
                float h2 = fmaxf(M1, o1);
                M1 = fminf(M1, o1);
                M2 = fminf(fminf(M2, o2), h2);
            }
            bip[g] = (int)(__float_as_uint(M1) & 0xFFu);
            float a1 = __uint_as_float(__float_as_uint(M1) & 0xFFFFFF00u);
            float a2 = __uint_as_float(__float_as_uint(M2) & 0xFFFFFF00u);
            // trunc-split bf16x3 error + packing quantization, 4x margin (half-units)
            float eps = fmaf(sqrtf(rn[g]), 1.5e-3f, fmaf(fabsf(a1), 3e-5f, 1e-6f));
            flg[g] = (a2 - a1) < eps;
        }

        // ---- rare: exact fp32 wave-cooperative rescan of ambiguous points ----
        #pragma unroll
        for (int g = 0; g < 2; ++g) {
            unsigned long long bm = __ballot((l < 16) && flg[g]);
            while (bm) {
                int p = __ffsll(bm) - 1;
                bm &= bm - 1;
                float rp[32];
                #pragma unroll
                for (int qq = 0; qq < 4; ++qq)
                    #pragma unroll
                    for (int j = 0; j < 8; ++j)
                        rp[qq*8 + j] = __shfl(r[g][j], qq*16 + p);
                float bests = FLTMAX; int bestk = 0;
                #pragma unroll
                for (int c = 0; c < 4; ++c) {
                    int k = (c << 6) + l;
                    const float4* ck = (const float4*)(cbq + (size_t)k * DIMS);
                    float a0=0.f,a1=0.f,a2=0.f,a3=0.f;
                    #pragma unroll
                    for (int j = 0; j < 8; ++j) {
                        float4 f = ck[j];
                        a0 = fmaf(rp[4*j+0], f.x, a0);
                        a1 = fmaf(rp[4*j+1], f.y, a1);
                        a2 = fmaf(rp[4*j+2], f.z, a2);
                        a3 = fmaf(rp[4*j+3], f.w, a3);
                    }
                    float sc = fmaf(-2.f, (a0+a1)+(a2+a3), 2.f * hnq[k]);
                    bool lt = sc < bests;
                    bests = lt ? sc : bests;  bestk = lt ? k : bestk;
                }
                #pragma unroll
                for (int off = 1; off < 64; off <<= 1) {
                    float so = __shfl_xor(bests, off);
                    int   ko = __shfl_xor(bestk, off);
                    bool take = (so < bests) || (so == bests && ko < bestk);
                    bests = take ? so : bests;
                    bestk = take ? ko : bestk;
                }
                if (cl == p) bip[g] = bestk;
            }
        }

        // ---- gather chosen codes (exact fp32), update residual, loss, indices ----
        #pragma unroll
        for (int g = 0; g < 2; ++g) {
            const float4* cq = (const float4*)(cbq + (size_t)bip[g] * DIMS + qo * 8);
            float4 c0 = cq[0], c1 = cq[1];
            r[g][0]-=c0.x; r[g][1]-=c0.y; r[g][2]-=c0.z; r[g][3]-=c0.w;
            r[g][4]-=c1.x; r[g][5]-=c1.y; r[g][6]-=c1.z; r[g][7]-=c1.w;
            #pragma unroll
            for (int j = 0; j < 8; ++j) la = fmaf(r[g][j], r[g][j], la);
            if (l < 16)
                out_idx[(size_t)(base + g*16 + l) * NQ + q] = (float)bip[g];
        }
    }

    // ---- epilogue: x_q = x - r_final ----
    #pragma unroll
    for (int g = 0; g < 2; ++g) {
        size_t o = (size_t)(base + g*16 + cl) * DIMS + qo * 8;
        const float4* xp = (const float4*)(x + o);
        float4 a = xp[0], c = xp[1];
        float4* op = (float4*)(out_xq + o);
        op[0] = make_float4(a.x - r[g][0], a.y - r[g][1], a.z - r[g][2], a.w - r[g][3]);
        op[1] = make_float4(c.x - r[g][4], c.y - r[g][5], c.z - r[g][6], c.w - r[g][7]);
    }

    // ---- loss: wave -> block -> one atomicAdd ----
    float v = la;
    #pragma unroll
    for (int off = 1; off < 64; off <<= 1)
        v += __shfl_xor(v, off);
    if (l == 0) s_ws[w] = v;
    __syncthreads();
    if (t == 0) {
        const float scale = (1.0f + BETA) / ((float)NQ * 262144.0f * (float)DIMS);
        atomicAdd(out_loss, (s_ws[0] + s_ws[1] + s_ws[2] + s_ws[3]) * scale);
    }
}

extern "C" void kernel_launch(void* const* d_in, const int* in_sizes, int n_in,
                              void* d_out, int out_size, void* d_ws, size_t ws_size,
                              hipStream_t stream) {
    const float* x  = (const float*)d_in[0];   // [N, 32]
    const float* cb = (const float*)d_in[1];   // [4, 256, 32]
    float* out = (float*)d_out;

    const int N = in_sizes[0] / DIMS;          // 262144
    float* out_xq   = out;
    float* out_loss = out + (size_t)N * DIMS;
    float* out_idx  = out + (size_t)N * DIMS + 1;

    // workspace layout: hi [4*1024*16B] | lo [4*1024*16B] | hn [4*256*4B] = 132 KB
    short* ws_hi = (short*)d_ws;
    short* ws_lo = (short*)((char*)d_ws + 65536);
    float* ws_hn = (float*)((char*)d_ws + 131072);

    rvq_prep<<<dim3(NQ), dim3(KC), 0, stream>>>(cb, ws_hi, ws_lo, ws_hn, out_loss);
    rvq_kernel<<<dim3(N / 128), dim3(256), 0, stream>>>(x, cb, ws_hi, ws_lo, ws_hn,
                                                        out_xq, out_loss, out_idx);
}

// Round 7
// 180.879 us; speedup vs baseline: 1.2392x; 1.1318x over previous
//
#include <hip/hip_runtime.h>

// Problem constants: N=262144, D=32, Q=4, K=256
#define DIMS 32
#define NQ   4
#define KC   256
#define BETA 0.25f
#define FLTMAX 3.402823466e38f

typedef __attribute__((ext_vector_type(8))) short  short8;   // 8 bf16 (4 VGPRs)
typedef __attribute__((ext_vector_type(4))) float  floatx4;  // MFMA acc

// ROUND-15 == ROUND-13 RESUBMIT #2 (r5 AND r6 were broker/infra failures:
// "MI355X container failed twice", no compile/correctness/counter signal
// either time; source audited for container-killers: no data-dependent
// unbounded loops, no divergent barriers, no inline asm, no exotic builtins
// beyond fmed3f). Rationale unchanged from r13:
// r12 ablation: removing ALL barriers/staging changed nothing -> bottleneck is
// the per-wave VALU+latency chain (10.3k VALU insts/wave measured, 68us pure-
// VALU floor, 2.2x latency gap at 4 waves/SIMD residency).
// This round trims both terms:
//  * fmed3 second-min: m2' = med3(pm, m1, m2) == min(m2, max(pm, m1)) under
//    the m1<=m2 invariant. -1 VALU per score (128 scores/lane/stage).
//  * DEFERRED +hrn: acc init = hn only. hrn is a per-POINT constant; all
//    min-merges compare scores of the SAME point, so argmin and the a2-a1
//    gap are shift-invariant. Negative packed scores still order correctly
//    under fminf; within-quantum flips stay inside the eps window (the
//    3e-5*|a1| term is the packed-domain quantization bound) -> exact rescan
//    covers them. Removes 128 adds/stage/wave + the hn+hrn dep ahead of each
//    MFMA chain; rn shuffle-reduce moves off the pre-tile critical path.
//    (r2 bundled this with a bad permlane asm; if absmax fails THIS round,
//    deferred-hrn is the culprit -- clean attribution.)
//  * Manual 2-deep tile prefetch (full unroll): 3 tiles x 8 regs in flight
//    (~24 VGPR) vs unroll-4's ~32, targeting VGPR<=102 -> 5 waves/SIMD.
// Everything else bit-identical to r12.

__global__ void rvq_prep(const float* __restrict__ cb,      // [NQ, KC, DIMS]
                         short* __restrict__ ws_hi,         // [NQ*1024*8]
                         short* __restrict__ ws_lo,         // [NQ*1024*8]
                         float* __restrict__ ws_hn,         // [NQ*KC]
                         float* __restrict__ out_loss)
{
    const int q = blockIdx.x;
    const int t = threadIdx.x;
    if (q == 0 && t == 0) *out_loss = 0.f;
    const float* cbq = cb + (size_t)q * KC * DIMS;

    // exact fp32 half-norms, thread t <-> code t
    {
        const float4* c4 = (const float4*)(cbq + (size_t)t * DIMS);
        float s0 = 0.f, s1 = 0.f, s2 = 0.f, s3 = 0.f;
        #pragma unroll
        for (int j = 0; j < 8; ++j) {
            float4 f = c4[j];
            s0 = fmaf(f.x, f.x, s0); s1 = fmaf(f.y, f.y, s1);
            s2 = fmaf(f.z, f.z, s2); s3 = fmaf(f.w, f.w, s3);
        }
        ws_hn[(q << 8) + t] = 0.5f * ((s0 + s1) + (s2 + s3));
    }

    // negated trunc-split codebook; entry e = tt*64 + qo*16 + cl, 16 B each
    #pragma unroll
    for (int it = 0; it < 4; ++it) {
        int e = it * 256 + t;
        const float4* src = (const float4*)(cbq + (size_t)((e >> 6) * 16 + (e & 15)) * DIMS
                                            + ((e >> 4) & 3) * 8);
        float4 f0 = src[0], f1 = src[1];
        unsigned u[8];
        u[0]=__float_as_uint(f0.x)^0x80000000u; u[1]=__float_as_uint(f0.y)^0x80000000u;
        u[2]=__float_as_uint(f0.z)^0x80000000u; u[3]=__float_as_uint(f0.w)^0x80000000u;
        u[4]=__float_as_uint(f1.x)^0x80000000u; u[5]=__float_as_uint(f1.y)^0x80000000u;
        u[6]=__float_as_uint(f1.z)^0x80000000u; u[7]=__float_as_uint(f1.w)^0x80000000u;
        int4 hp, lp;
        int* hpi = (int*)&hp; int* lpi = (int*)&lp;
        #pragma unroll
        for (int p = 0; p < 4; ++p) {
            unsigned a = u[2*p], b = u[2*p+1];
            hpi[p] = (int)((b & 0xFFFF0000u) | (a >> 16));
            float ea = __uint_as_float(a) - __uint_as_float(a & 0xFFFF0000u);
            float eb = __uint_as_float(b) - __uint_as_float(b & 0xFFFF0000u);
            unsigned ua = __float_as_uint(ea), ub = __float_as_uint(eb);
            lpi[p] = (int)((ub & 0xFFFF0000u) | (ua >> 16));
        }
        *(int4*)(&ws_hi[(size_t)((q << 10) + e) << 3]) = hp;
        *(int4*)(&ws_lo[(size_t)((q << 10) + e) << 3]) = lp;
    }
}

__launch_bounds__(256, 2)
__global__ void rvq_kernel(const float* __restrict__ x,
                           const float* __restrict__ cb,      // [NQ, KC, DIMS] fp32 (gather/rescan)
                           const short* __restrict__ ws_hi,   // preconverted hi (L2-resident)
                           const short* __restrict__ ws_lo,   // preconverted lo (L2-resident)
                           const float* __restrict__ ws_hn,   // half-norms
                           float* __restrict__ out_xq,        // [N, DIMS]
                           float* __restrict__ out_loss,      // [1] pre-zeroed by prep
                           float* __restrict__ out_idx)       // [N, NQ] as float
{
    __shared__ float s_hn[NQ * KC];                  // 4 KB: 0.5*||c||^2, all stages
    __shared__ float s_ws[4];

    const int t  = threadIdx.x;
    const int l  = t & 63;
    const int w  = t >> 6;
    const int qo = l >> 4;       // dim-octet (0..3)
    const int cl = l & 15;       // point-in-group / code-in-tile

    const int base = blockIdx.x * 128 + w * 32;   // wave covers 32 points (2 groups of 16)

    // ---- all-stage half-norms into LDS once ----
    #pragma unroll
    for (int i = 0; i < 4; ++i) s_hn[(i << 8) + t] = ws_hn[(i << 8) + t];

    // ---- residuals: [group][8 dims], 16 VGPRs ----
    float r[2][8];
    #pragma unroll
    for (int g = 0; g < 2; ++g) {
        const float4* xp = (const float4*)(x + (size_t)(base + g*16 + cl) * DIMS + qo * 8);
        float4 a = xp[0], c = xp[1];
        r[g][0]=a.x; r[g][1]=a.y; r[g][2]=a.z; r[g][3]=a.w;
        r[g][4]=c.x; r[g][5]=c.y; r[g][6]=c.z; r[g][7]=c.w;
    }

    __syncthreads();   // s_hn ready (the ONLY barrier until the loss epilogue)

    float la = 0.f;   // sum over own dims of ||r_new||^2, all stages

    for (int q = 0; q < NQ; ++q) {
        const float* cbq = cb + (size_t)q * KC * DIMS;
        const float* hnq = &s_hn[q << 8];
        const short8* gh  = (const short8*)(ws_hi + ((size_t)q << 13));  // 1024 entries
        const short8* gl8 = (const short8*)(ws_lo + ((size_t)q << 13));

        // ---- B-fragments: trunc-split bf16 of residual (unnegated) ----
        short8 rh[2], rl[2];
        #pragma unroll
        for (int g = 0; g < 2; ++g) {
            int4 hp, lp;
            int* hpi = (int*)&hp; int* lpi = (int*)&lp;
            #pragma unroll
            for (int p = 0; p < 4; ++p) {
                unsigned a = __float_as_uint(r[g][2*p]);
                unsigned b = __float_as_uint(r[g][2*p+1]);
                hpi[p] = (int)((b & 0xFFFF0000u) | (a >> 16));
                float ea = r[g][2*p]   - __uint_as_float(a & 0xFFFF0000u);
                float eb = r[g][2*p+1] - __uint_as_float(b & 0xFFFF0000u);
                unsigned ua = __float_as_uint(ea), ub = __float_as_uint(eb);
                lpi[p] = (int)((ub & 0xFFFF0000u) | (ua >> 16));
            }
            rh[g] = *(short8*)&hp;
            rl[g] = *(short8*)&lp;
        }

        // ---- MFMA tile loop: acc init = hn ONLY (hrn deferred, shift-invariant);
        //      2-deep register prefetch pipeline over 16 tiles ----
        float m1[2][4], m2[2][4];
        #pragma unroll
        for (int g = 0; g < 2; ++g)
            #pragma unroll
            for (int i = 0; i < 4; ++i) { m1[g][i] = FLTMAX; m2[g][i] = FLTMAX; }

        short8 chA = gh[l],      clA = gl8[l];
        short8 chB = gh[64 + l], clB = gl8[64 + l];
        #pragma unroll
        for (int tt = 0; tt < 16; ++tt) {
            short8 chC = chA, clC = clA;   // dead on last 2 iters
            if (tt + 2 < 16) { chC = gh[((tt+2) << 6) + l]; clC = gl8[((tt+2) << 6) + l]; }
            const float4 hn4 = *(const float4*)(&hnq[(tt << 4) + (qo << 2)]);  // LDS broadcast
            #pragma unroll
            for (int g = 0; g < 2; ++g) {
                floatx4 acc = {hn4.x, hn4.y, hn4.z, hn4.w};
                acc = __builtin_amdgcn_mfma_f32_16x16x32_bf16(chA, rh[g], acc, 0, 0, 0);
                acc = __builtin_amdgcn_mfma_f32_16x16x32_bf16(chA, rl[g], acc, 0, 0, 0);
                acc = __builtin_amdgcn_mfma_f32_16x16x32_bf16(clA, rh[g], acc, 0, 0, 0);
                #pragma unroll
                for (int i = 0; i < 4; ++i) {
                    float pm = __uint_as_float((__float_as_uint(acc[i]) & 0xFFFFFF00u)
                                               | (unsigned)((tt << 2) | i));
                    m2[g][i] = __builtin_amdgcn_fmed3f(pm, m1[g][i], m2[g][i]);
                    m1[g][i] = fminf(pm, m1[g][i]);
                }
            }
            chA = chB; clA = clB; chB = chC; clB = clC;
        }

        // ---- ||r||^2 per point (consumed only by eps below; off critical path) ----
        float rn[2];
        #pragma unroll
        for (int g = 0; g < 2; ++g) {
            float p0 = 0.f;
            #pragma unroll
            for (int j = 0; j < 8; ++j) p0 = fmaf(r[g][j], r[g][j], p0);
            p0 += __shfl_xor(p0, 16);
            p0 += __shfl_xor(p0, 32);
            rn[g] = p0;
        }

        int bip[2]; bool flg[2];
        #pragma unroll
        for (int g = 0; g < 2; ++g) {
            // resolve packed (tt<<2)|i -> full code tt*16 + qo*4 + i (order-preserving)
            #pragma unroll
            for (int i = 0; i < 4; ++i) {
                unsigned u = __float_as_uint(m1[g][i]);
                unsigned low = u & 0xFFu;
                unsigned full = ((low & 0xFCu) << 2) | ((unsigned)qo << 2) | (low & 3u);
                m1[g][i] = __uint_as_float((u & 0xFFFFFF00u) | full);
            }
            // merge 4 regs -> (M1, M2)
            float p1 = fminf(m1[g][0], m1[g][1]);
            float ph = fmaxf(m1[g][0], m1[g][1]);
            float p2 = fminf(fminf(m2[g][0], m2[g][1]), ph);
            float s1 = fminf(m1[g][2], m1[g][3]);
            float sh = fmaxf(m1[g][2], m1[g][3]);
            float s2 = fminf(fminf(m2[g][2], m2[g][3]), sh);
            float hh = fmaxf(p1, s1);
            float M1 = fminf(p1, s1);
            float M2 = fminf(fminf(p2, s2), hh);
            // merge across the 4 owner lanes (xor 16, 32) — lands where it's consumed
            #pragma unroll
            for (int off = 16; off <= 32; off <<= 1) {
                float o1 = __shfl_xor(M1, off);
                float o2 = __shfl_xor(M2, off);
                float h2 = fmaxf(M1, o1);
                M1 = fminf(M1, o1);
                M2 = fminf(fminf(M2, o2), h2);
            }
            bip[g] = (int)(__float_as_uint(M1) & 0xFFu);
            float a1 = __uint_as_float(__float_as_uint(M1) & 0xFFFFFF00u);
            float a2 = __uint_as_float(__float_as_uint(M2) & 0xFFFFFF00u);
            // trunc-split bf16x3 error + packing quantization (packed-domain |a1|),
            // 4x margin (half-units). Gap a2-a1 is hrn-shift-invariant.
            float eps = fmaf(sqrtf(rn[g]), 1.5e-3f, fmaf(fabsf(a1), 3e-5f, 1e-6f));
            flg[g] = (a2 - a1) < eps;
        }

        // ---- rare: exact fp32 wave-cooperative rescan of ambiguous points ----
        #pragma unroll
        for (int g = 0; g < 2; ++g) {
            unsigned long long bm = __ballot((l < 16) && flg[g]);
            while (bm) {
                int p = __ffsll(bm) - 1;
                bm &= bm - 1;
                float rp[32];
                #pragma unroll
                for (int qq = 0; qq < 4; ++qq)
                    #pragma unroll
                    for (int j = 0; j < 8; ++j)
                        rp[qq*8 + j] = __shfl(r[g][j], qq*16 + p);
                float bests = FLTMAX; int bestk = 0;
                #pragma unroll
                for (int c = 0; c < 4; ++c) {
                    int k = (c << 6) + l;
                    const float4* ck = (const float4*)(cbq + (size_t)k * DIMS);
                    float a0=0.f,a1=0.f,a2=0.f,a3=0.f;
                    #pragma unroll
                    for (int j = 0; j < 8; ++j) {
                        float4 f = ck[j];
                        a0 = fmaf(rp[4*j+0], f.x, a0);
                        a1 = fmaf(rp[4*j+1], f.y, a1);
                        a2 = fmaf(rp[4*j+2], f.z, a2);
                        a3 = fmaf(rp[4*j+3], f.w, a3);
                    }
                    float sc = fmaf(-2.f, (a0+a1)+(a2+a3), 2.f * hnq[k]);
                    bool lt = sc < bests;
                    bests = lt ? sc : bests;  bestk = lt ? k : bestk;
                }
                #pragma unroll
                for (int off = 1; off < 64; off <<= 1) {
                    float so = __shfl_xor(bests, off);
                    int   ko = __shfl_xor(bestk, off);
                    bool take = (so < bests) || (so == bests && ko < bestk);
                    bests = take ? so : bests;
                    bestk = take ? ko : bestk;
                }
                if (cl == p) bip[g] = bestk;
            }
        }

        // ---- gather chosen codes (exact fp32), update residual, loss, indices ----
        #pragma unroll
        for (int g = 0; g < 2; ++g) {
            const float4* cq = (const float4*)(cbq + (size_t)bip[g] * DIMS + qo * 8);
            float4 c0 = cq[0], c1 = cq[1];
            r[g][0]-=c0.x; r[g][1]-=c0.y; r[g][2]-=c0.z; r[g][3]-=c0.w;
            r[g][4]-=c1.x; r[g][5]-=c1.y; r[g][6]-=c1.z; r[g][7]-=c1.w;
            #pragma unroll
            for (int j = 0; j < 8; ++j) la = fmaf(r[g][j], r[g][j], la);
            if (l < 16)
                out_idx[(size_t)(base + g*16 + l) * NQ + q] = (float)bip[g];
        }
    }

    // ---- epilogue: x_q = x - r_final ----
    #pragma unroll
    for (int g = 0; g < 2; ++g) {
        size_t o = (size_t)(base + g*16 + cl) * DIMS + qo * 8;
        const float4* xp = (const float4*)(x + o);
        float4 a = xp[0], c = xp[1];
        float4* op = (float4*)(out_xq + o);
        op[0] = make_float4(a.x - r[g][0], a.y - r[g][1], a.z - r[g][2], a.w - r[g][3]);
        op[1] = make_float4(c.x - r[g][4], c.y - r[g][5], c.z - r[g][6], c.w - r[g][7]);
    }

    // ---- loss: wave -> block -> one atomicAdd ----
    float v = la;
    #pragma unroll
    for (int off = 1; off < 64; off <<= 1)
        v += __shfl_xor(v, off);
    if (l == 0) s_ws[w] = v;
    __syncthreads();
    if (t == 0) {
        const float scale = (1.0f + BETA) / ((float)NQ * 262144.0f * (float)DIMS);
        atomicAdd(out_loss, (s_ws[0] + s_ws[1] + s_ws[2] + s_ws[3]) * scale);
    }
}

extern "C" void kernel_launch(void* const* d_in, const int* in_sizes, int n_in,
                              void* d_out, int out_size, void* d_ws, size_t ws_size,
                              hipStream_t stream) {
    const float* x  = (const float*)d_in[0];   // [N, 32]
    const float* cb = (const float*)d_in[1];   // [4, 256, 32]
    float* out = (float*)d_out;

    const int N = in_sizes[0] / DIMS;          // 262144
    float* out_xq   = out;
    float* out_loss = out + (size_t)N * DIMS;
    float* out_idx  = out + (size_t)N * DIMS + 1;

    // workspace layout: hi [4*1024*16B] | lo [4*1024*16B] | hn [4*256*4B] = 132 KB
    short* ws_hi = (short*)d_ws;
    short* ws_lo = (short*)((char*)d_ws + 65536);
    float* ws_hn = (float*)((char*)d_ws + 131072);

    rvq_prep<<<dim3(NQ), dim3(KC), 0, stream>>>(cb, ws_hi, ws_lo, ws_hn, out_loss);
    rvq_kernel<<<dim3(N / 128), dim3(256), 0, stream>>>(x, cb, ws_hi, ws_lo, ws_hn,
                                                        out_xq, out_loss, out_idx);
}